// Round 6
// baseline (393.681 us; speedup 1.0000x reference)
//
#include <hip/hip_runtime.h>
#include <hip/hip_bf16.h>

#define DIM 512
#define BATCH 512
#define CCLS 100000
#define BN 128
#define NT 782   // ceil(100000/128)

typedef __attribute__((ext_vector_type(4))) float f32x4;

__device__ __forceinline__ void async_copy16(const unsigned char* g, unsigned char* l) {
  __builtin_amdgcn_global_load_lds((const __attribute__((address_space(1))) void*)g,
                                   (__attribute__((address_space(3))) void*)l, 16, 0, 0);
}

// One wave per row of x: quantize RAW x to fp8 e4m3 (no normalization --
// norms divided out in the GEMM epilogue), emit nx[row] = |x_row|.
__global__ __launch_bounds__(256) void xquant(const float* __restrict__ x,
                                              unsigned char* __restrict__ xq,
                                              float* __restrict__ nx) {
  int wave = threadIdx.x >> 6;
  int lane = threadIdx.x & 63;
  int row = blockIdx.x * 4 + wave;           // 512 rows, 128 blocks
  const float4* src = (const float4*)(x + (size_t)row * DIM);
  float4 v0 = src[2 * lane];
  float4 v1 = src[2 * lane + 1];
  float ss = v0.x*v0.x + v0.y*v0.y + v0.z*v0.z + v0.w*v0.w
           + v1.x*v1.x + v1.y*v1.y + v1.z*v1.z + v1.w*v1.w;
  #pragma unroll
  for (int off = 32; off > 0; off >>= 1) ss += __shfl_xor(ss, off, 64);
  int p0 = __builtin_amdgcn_cvt_pk_fp8_f32(v0.x, v0.y, 0, false);
  p0     = __builtin_amdgcn_cvt_pk_fp8_f32(v0.z, v0.w, p0, true);
  int p1 = __builtin_amdgcn_cvt_pk_fp8_f32(v1.x, v1.y, 0, false);
  p1     = __builtin_amdgcn_cvt_pk_fp8_f32(v1.z, v1.w, p1, true);
  ((int2*)(xq + (size_t)row * DIM))[lane] = make_int2(p0, p1);
  if (lane == 0) nx[row] = fmaxf(sqrtf(ss), 1e-12f);
}

// Fused wt-quantization + 512x128 fp8 GEMM + CosFace epilogue.
// One block per nt tile (782 blocks, 1024 threads = 16 waves, 4m x 4n,
// per-wave 128x32, acc 8x2 f32x4 = 64 VGPR -- R0's proven cap-128 budget).
// wt is read ONCE from HBM (fp32), scaled x16 into e4m3 range, quantized
// in-register, ds_write'd into the chunk-XOR-swizzled B tile; per-row
// sum-of-squares accumulates in LDS across the 4 K-tiles. Epilogue computes
// cos = dot / (|16w| * |x|) -- normalization error class identical to the
// previous normalize-then-quantize scheme. Removes the 41 us rownorm pass
// and the wn round-trip entirely; normalization traffic hides under MFMA.
// Non-scaled mfma_f32_16x16x32_fp8_fp8: 64 MFMA per wave per K-tile keeps
// the barrier interval compute-fat (the MX variants' fatal flaw).
__global__ __launch_bounds__(1024) void cosface_fused(
    const unsigned char* __restrict__ xq,
    const float* __restrict__ wt,
    const int* __restrict__ gt,
    const float* __restrict__ nx,
    float* __restrict__ partial,
    float* __restrict__ tgt) {
  __shared__ __align__(16) unsigned char lds_a[512 * 128];   // 64 KB
  __shared__ __align__(16) unsigned char lds_b[BN * 128];    // 16 KB
  __shared__ float lds_rowsum[BATCH];
  __shared__ float lds_nx[BATCH];
  __shared__ float lds_nw[BN];
  __shared__ int lds_gt[BATCH];

  const int tid = threadIdx.x;
  const int lane = tid & 63;
  const int w = tid >> 6;          // wave 0..15
  const int wm = w >> 2;           // 0..3  (128-row slice)
  const int wn_ = w & 3;           // 0..3  (32-col slice)
  const int nt = blockIdx.x;       // 0..781

  if (tid < BATCH) {
    lds_rowsum[tid] = 0.f;
    lds_gt[tid] = gt[tid];
    lds_nx[tid] = nx[tid];
  }
  if (tid < BN) lds_nw[tid] = 0.f;

  // A staging: 4096 chunks of 16B (512 rows x 8 chunks), 4/thread.
  // chunk c -> row m = c>>3, slot qs = c&7, global chunk qg = qs ^ (m&7).
  unsigned int oa[4];
  #pragma unroll
  for (int j = 0; j < 4; ++j) {
    int c = j * 1024 + tid;
    int m = c >> 3;
    int qg = (c & 7) ^ (m & 7);
    oa[j] = (unsigned int)m * DIM + qg * 16;
  }
  // B staging: 1024 chunks, exactly 1/thread; source is fp32 wt.
  const int mB = tid >> 3;                 // local class row 0..127
  const int qgB = (tid & 7) ^ (mB & 7);    // global k-chunk this slot holds
  int rowB = nt * BN + mB;
  if (rowB >= CCLS) rowB = CCLS - 1;       // clamp; excluded in epilogue
  const float* wsrc = wt + (size_t)rowB * DIM + qgB * 16;

  f32x4 acc[8][2];
  #pragma unroll
  for (int i = 0; i < 8; ++i)
    #pragma unroll
    for (int j = 0; j < 2; ++j)
      acc[i][j] = (f32x4){0.f, 0.f, 0.f, 0.f};

  const int quad = lane >> 4;
  const int l15 = lane & 15;
  const int sw = l15 & 7;          // (row & 7) for all fragment rows
  __syncthreads();                 // lds_nw/rowsum init visible before atomics

  for (int kk = 0; kk < 4; ++kk) {
    // Stage A (async, fp8 direct to LDS).
    #pragma unroll
    for (int j = 0; j < 4; ++j)
      async_copy16(xq + oa[j] + kk * 128, &lds_a[(j * 1024 + w * 64) * 16]);
    // Stage B: read 16 fp32, scale x16, quantize, one ds_write_b128.
    {
      const float* p = wsrc + kk * 128;
      float4 f0 = *(const float4*)(p);
      float4 f1 = *(const float4*)(p + 4);
      float4 f2 = *(const float4*)(p + 8);
      float4 f3 = *(const float4*)(p + 12);
      f0.x*=16.f; f0.y*=16.f; f0.z*=16.f; f0.w*=16.f;
      f1.x*=16.f; f1.y*=16.f; f1.z*=16.f; f1.w*=16.f;
      f2.x*=16.f; f2.y*=16.f; f2.z*=16.f; f2.w*=16.f;
      f3.x*=16.f; f3.y*=16.f; f3.z*=16.f; f3.w*=16.f;
      float ss = f0.x*f0.x + f0.y*f0.y + f0.z*f0.z + f0.w*f0.w
               + f1.x*f1.x + f1.y*f1.y + f1.z*f1.z + f1.w*f1.w
               + f2.x*f2.x + f2.y*f2.y + f2.z*f2.z + f2.w*f2.w
               + f3.x*f3.x + f3.y*f3.y + f3.z*f3.z + f3.w*f3.w;
      int p0 = __builtin_amdgcn_cvt_pk_fp8_f32(f0.x, f0.y, 0, false);
      p0     = __builtin_amdgcn_cvt_pk_fp8_f32(f0.z, f0.w, p0, true);
      int p1 = __builtin_amdgcn_cvt_pk_fp8_f32(f1.x, f1.y, 0, false);
      p1     = __builtin_amdgcn_cvt_pk_fp8_f32(f1.z, f1.w, p1, true);
      int p2 = __builtin_amdgcn_cvt_pk_fp8_f32(f2.x, f2.y, 0, false);
      p2     = __builtin_amdgcn_cvt_pk_fp8_f32(f2.z, f2.w, p2, true);
      int p3 = __builtin_amdgcn_cvt_pk_fp8_f32(f3.x, f3.y, 0, false);
      p3     = __builtin_amdgcn_cvt_pk_fp8_f32(f3.z, f3.w, p3, true);
      ((int4*)lds_b)[tid] = make_int4(p0, p1, p2, p3);
      // 8 consecutive lanes own one row: reduce ss, leader accumulates.
      ss += __shfl_xor(ss, 1, 64);
      ss += __shfl_xor(ss, 2, 64);
      ss += __shfl_xor(ss, 4, 64);
      if ((lane & 7) == 0) atomicAdd(&lds_nw[mB], ss);
    }
    __syncthreads();

    // Compute: 4 k-slices x 16 MFMA per wave (64 MFMA per barrier interval).
    #pragma unroll
    for (int s = 0; s < 4; ++s) {
      int g = s * 4 + quad;
      int cs = g >> 1;
      int h = (g & 1) * 8;
      long long af[8], bf[2];
      #pragma unroll
      for (int i = 0; i < 8; ++i)
        af[i] = *(const long long*)&lds_a[(wm * 128 + i * 16 + l15) * 128 + ((cs ^ sw) * 16) + h];
      #pragma unroll
      for (int j = 0; j < 2; ++j)
        bf[j] = *(const long long*)&lds_b[(wn_ * 32 + j * 16 + l15) * 128 + ((cs ^ sw) * 16) + h];
      #pragma unroll
      for (int i = 0; i < 8; ++i)
        #pragma unroll
        for (int j = 0; j < 2; ++j)
          acc[i][j] = __builtin_amdgcn_mfma_f32_16x16x32_fp8_fp8(af[i], bf[j], acc[i][j], 0, 0, 0);
    }
    __syncthreads();
  }

  // Epilogue: cos = acc/(nw*nx); logit = 64*cos (-22.4 at gt);
  // rowsum += sum_n exp(logit-64).
  float rnw[2];
  #pragma unroll
  for (int j = 0; j < 2; ++j)
    rnw[j] = 1.0f / fmaxf(sqrtf(lds_nw[wn_ * 32 + j * 16 + l15]), 1e-12f);
  #pragma unroll
  for (int i = 0; i < 8; ++i) {
    #pragma unroll
    for (int reg = 0; reg < 4; ++reg) {
      int m_loc = wm * 128 + i * 16 + quad * 4 + reg;
      int gtm = lds_gt[m_loc];
      float rx = 64.0f / lds_nx[m_loc];     // fold SCALE into the division
      float s = 0.f;
      #pragma unroll
      for (int j = 0; j < 2; ++j) {
        int n_g = nt * BN + wn_ * 32 + j * 16 + l15;
        float logit = acc[i][j][reg] * rnw[j] * rx;
        if (n_g == gtm) {
          logit -= 64.f * 0.35f;
          tgt[m_loc] = logit;
        }
        if (n_g < CCLS) s += __expf(logit - 64.f);
      }
      #pragma unroll
      for (int off = 1; off < 16; off <<= 1) s += __shfl_xor(s, off, 64);
      if (l15 == 0) atomicAdd(&lds_rowsum[m_loc], s);
    }
  }
  __syncthreads();
  if (tid < BATCH)
    partial[(size_t)tid * NT + nt] = lds_rowsum[tid];
}

// One wave per row m: sum partial[m][0..NT) (contiguous), emit nll[m].
__global__ __launch_bounds__(64) void nll_rows(const float* __restrict__ partial,
                                               const float* __restrict__ tgt,
                                               float* __restrict__ nll) {
  int m = blockIdx.x;
  int lane = threadIdx.x;
  const float* row = partial + (size_t)m * NT;
  float s = 0.f;
  for (int t = lane; t < NT; t += 64) s += row[t];
  #pragma unroll
  for (int off = 32; off > 0; off >>= 1) s += __shfl_xor(s, off, 64);
  if (lane == 0) nll[m] = (logf(s) + 64.f) - tgt[m];
}

__global__ __launch_bounds__(512) void reduce_mean(const float* __restrict__ nll,
                                                   float* __restrict__ out) {
  __shared__ float red[BATCH];
  int m = threadIdx.x;
  red[m] = nll[m];
  __syncthreads();
  for (int k = 256; k > 0; k >>= 1) {
    if (m < k) red[m] += red[m + k];
    __syncthreads();
  }
  if (m == 0) out[0] = red[0] * (1.0f / BATCH);
}

extern "C" void kernel_launch(void* const* d_in, const int* in_sizes, int n_in,
                              void* d_out, int out_size, void* d_ws, size_t ws_size,
                              hipStream_t stream) {
  const float* x  = (const float*)d_in[0];
  const int*   gt = (const int*)d_in[1];
  const float* wt = (const float*)d_in[2];
  float* out = (float*)d_out;

  char* ws = (char*)d_ws;
  unsigned char* xq = (unsigned char*)ws;            //   262,144 B
  float* nx         = (float*)(ws + 262144);         //     2,048 B
  float* partial    = (float*)(ws + 264192);         // 1,601,536 B (512*782*4)
  float* tgt        = (float*)(ws + 1865728);        //     2,048 B
  float* nll        = (float*)(ws + 1867776);        //     2,048 B

  xquant<<<BATCH / 4, 256, 0, stream>>>(x, xq, nx);
  cosface_fused<<<NT, 1024, 0, stream>>>(xq, wt, gt, nx, partial, tgt);
  nll_rows<<<BATCH, 64, 0, stream>>>(partial, tgt, nll);
  reduce_mean<<<1, BATCH, 0, stream>>>(nll, out);
}

// Round 7
// 348.521 us; speedup vs baseline: 1.1296x; 1.1296x over previous
//
#include <hip/hip_runtime.h>
#include <hip/hip_bf16.h>

#define DIM 512
#define BATCH 512
#define CCLS 100000
#define BM 256
#define BN 64
#define NT 1563   // ceil(100000/64)

typedef __attribute__((ext_vector_type(4))) float f32x4;

__device__ __forceinline__ void async_copy16(const unsigned char* g, unsigned char* l) {
  __builtin_amdgcn_global_load_lds((const __attribute__((address_space(1))) void*)g,
                                   (__attribute__((address_space(3))) void*)l, 16, 0, 0);
}

// One wave per row of x: quantize RAW x to fp8 e4m3 (no normalization --
// norms divided out in the GEMM epilogue), emit nx[row] = |x_row|.
__global__ __launch_bounds__(256) void xquant(const float* __restrict__ x,
                                              unsigned char* __restrict__ xq,
                                              float* __restrict__ nx) {
  int wave = threadIdx.x >> 6;
  int lane = threadIdx.x & 63;
  int row = blockIdx.x * 4 + wave;           // 512 rows, 128 blocks
  const float4* src = (const float4*)(x + (size_t)row * DIM);
  float4 v0 = src[2 * lane];
  float4 v1 = src[2 * lane + 1];
  float ss = v0.x*v0.x + v0.y*v0.y + v0.z*v0.z + v0.w*v0.w
           + v1.x*v1.x + v1.y*v1.y + v1.z*v1.z + v1.w*v1.w;
  #pragma unroll
  for (int off = 32; off > 0; off >>= 1) ss += __shfl_xor(ss, off, 64);
  int p0 = __builtin_amdgcn_cvt_pk_fp8_f32(v0.x, v0.y, 0, false);
  p0     = __builtin_amdgcn_cvt_pk_fp8_f32(v0.z, v0.w, p0, true);
  int p1 = __builtin_amdgcn_cvt_pk_fp8_f32(v1.x, v1.y, 0, false);
  p1     = __builtin_amdgcn_cvt_pk_fp8_f32(v1.z, v1.w, p1, true);
  ((int2*)(xq + (size_t)row * DIM))[lane] = make_int2(p0, p1);
  if (lane == 0) nx[row] = fmaxf(sqrtf(ss), 1e-12f);
}

// Fused wt-quantize + 256x64 fp8 GEMM + CosFace epilogue.
// Register plan = R0's proven no-spill profile: 512 threads, (512,4) cap-128,
// acc[4][2] = 32 AGPR, arch live during MFMA ~45 (f-prefetch 16 + frags 12 +
// addr). LDS 44 KB -> 2 blocks/CU (cross-block TLP hides barrier drains).
// Per iter: [W: ds_write B(kk) from p-regs, A-async(kk), nw-atomic]
//           syncthreads  (drains exactly the A-asyncs -- B(kk+1) not issued)
//           [C: issue B-loads(kk+1) -> 32 MFMA from LDS]
//           [Q: quantize(kk+1) -> 5 regs]   (loads covered by phase C)
//           syncthreads  (nothing outstanding).
// wt read once per mt flavor; bijective XCD swizzle pairs mt=0/1 of the same
// nt on one XCD so the second read L2-hits. wn never materialized.
__global__ __launch_bounds__(512, 4) void cosface_fused(
    const unsigned char* __restrict__ xq,
    const float* __restrict__ wt,
    const int* __restrict__ gt,
    const float* __restrict__ nx,
    float* __restrict__ partial,
    float* __restrict__ tgt) {
  __shared__ __align__(16) unsigned char lds_a[BM * 128];   // 32 KB
  __shared__ __align__(16) unsigned char lds_b[BN * 128];   //  8 KB
  __shared__ float lds_rowsum[BM];
  __shared__ float lds_nx[BM];
  __shared__ float lds_nw[BN];
  __shared__ int lds_gt[BM];

  const int tid = threadIdx.x;
  const int lane = tid & 63;
  const int w = tid >> 6;          // wave 0..7
  const int wm = w >> 1;           // 0..3  (64-row slice)
  const int wn_ = w & 1;           // 0..1  (32-col slice)

  // Bijective chunked XCD swizzle: 3126 = 6*391 + 2*390.
  int flat = blockIdx.x;
  int xcd = flat & 7;
  int idx = flat >> 3;
  int f = ((xcd < 6) ? xcd * 391 : (6 * 391 + (xcd - 6) * 390)) + idx;
  const int mt = f & 1;            // 0..1
  const int nt = f >> 1;           // 0..1562

  if (tid < BM) {
    lds_rowsum[tid] = 0.f;
    lds_gt[tid] = gt[mt * BM + tid];
    lds_nx[tid] = nx[mt * BM + tid];
  }
  if (tid < BN) lds_nw[tid] = 0.f;

  // A staging (xq, fp8, L2-resident): 2048 chunks of 16B, 4/thread.
  // chunk c -> row m = c>>3, slot qs = c&7, global chunk qg = qs ^ (m&7).
  unsigned int oa[4];
  #pragma unroll
  for (int j = 0; j < 4; ++j) {
    int c = j * 512 + tid;
    int m = c >> 3;
    int qg = (c & 7) ^ (m & 7);
    oa[j] = (unsigned int)(mt * BM + m) * DIM + qg * 16;
  }
  // B staging source (fp32 wt): 512 chunks, 1/thread.
  const int mB = tid >> 3;                 // local class row 0..63
  const int qgB = (tid & 7) ^ (mB & 7);    // global k-chunk this slot holds
  int rowB = nt * BN + mB;
  if (rowB >= CCLS) rowB = CCLS - 1;       // clamp; excluded in epilogue
  const float* wsrc = wt + (size_t)rowB * DIM + qgB * 16;

  f32x4 acc[4][2];
  #pragma unroll
  for (int i = 0; i < 4; ++i)
    #pragma unroll
    for (int j = 0; j < 2; ++j)
      acc[i][j] = (f32x4){0.f, 0.f, 0.f, 0.f};

  const int quad = lane >> 4;
  const int l15 = lane & 15;
  const int sw = l15 & 7;          // (row & 7) for all fragment rows

  // Prologue: load + quantize B(0) -> p-regs (latency exposed once).
  int p0, p1, p2, p3;
  float ssq;
  {
    float4 f0 = *(const float4*)(wsrc);
    float4 f1 = *(const float4*)(wsrc + 4);
    float4 f2 = *(const float4*)(wsrc + 8);
    float4 f3 = *(const float4*)(wsrc + 12);
    f0.x*=16.f; f0.y*=16.f; f0.z*=16.f; f0.w*=16.f;
    f1.x*=16.f; f1.y*=16.f; f1.z*=16.f; f1.w*=16.f;
    f2.x*=16.f; f2.y*=16.f; f2.z*=16.f; f2.w*=16.f;
    f3.x*=16.f; f3.y*=16.f; f3.z*=16.f; f3.w*=16.f;
    ssq = f0.x*f0.x + f0.y*f0.y + f0.z*f0.z + f0.w*f0.w
        + f1.x*f1.x + f1.y*f1.y + f1.z*f1.z + f1.w*f1.w
        + f2.x*f2.x + f2.y*f2.y + f2.z*f2.z + f2.w*f2.w
        + f3.x*f3.x + f3.y*f3.y + f3.z*f3.z + f3.w*f3.w;
    p0 = __builtin_amdgcn_cvt_pk_fp8_f32(f0.x, f0.y, 0, false);
    p0 = __builtin_amdgcn_cvt_pk_fp8_f32(f0.z, f0.w, p0, true);
    p1 = __builtin_amdgcn_cvt_pk_fp8_f32(f1.x, f1.y, 0, false);
    p1 = __builtin_amdgcn_cvt_pk_fp8_f32(f1.z, f1.w, p1, true);
    p2 = __builtin_amdgcn_cvt_pk_fp8_f32(f2.x, f2.y, 0, false);
    p2 = __builtin_amdgcn_cvt_pk_fp8_f32(f2.z, f2.w, p2, true);
    p3 = __builtin_amdgcn_cvt_pk_fp8_f32(f3.x, f3.y, 0, false);
    p3 = __builtin_amdgcn_cvt_pk_fp8_f32(f3.z, f3.w, p3, true);
  }
  __syncthreads();   // init (rowsum/nw/gt/nx) visible before phase-W atomics

  for (int kk = 0; kk < 4; ++kk) {
    // --- Phase W: publish B(kk), stage A(kk), accumulate |16w|^2.
    ((int4*)lds_b)[tid] = make_int4(p0, p1, p2, p3);
    #pragma unroll
    for (int j = 0; j < 4; ++j)
      async_copy16(xq + oa[j] + kk * 128, &lds_a[(j * 512 + w * 64) * 16]);
    {
      float s = ssq;
      s += __shfl_xor(s, 1, 64);
      s += __shfl_xor(s, 2, 64);
      s += __shfl_xor(s, 4, 64);
      if ((lane & 7) == 0) atomicAdd(&lds_nw[mB], s);
    }
    __syncthreads();   // drains the 4 A-asyncs; B(kk+1) loads not yet issued

    // --- Phase C: issue B-loads(kk+1), then compute tile kk.
    float4 f0, f1, f2, f3;
    if (kk < 3) {
      const float* p = wsrc + (kk + 1) * 128;
      f0 = *(const float4*)(p);
      f1 = *(const float4*)(p + 4);
      f2 = *(const float4*)(p + 8);
      f3 = *(const float4*)(p + 12);
    }
    #pragma unroll
    for (int s = 0; s < 4; ++s) {
      int g = s * 4 + quad;
      int cs = g >> 1;
      int h = (g & 1) * 8;
      long long af[4], bf[2];
      #pragma unroll
      for (int i = 0; i < 4; ++i)
        af[i] = *(const long long*)&lds_a[(wm * 64 + i * 16 + l15) * 128 + ((cs ^ sw) * 16) + h];
      #pragma unroll
      for (int j = 0; j < 2; ++j)
        bf[j] = *(const long long*)&lds_b[(wn_ * 32 + j * 16 + l15) * 128 + ((cs ^ sw) * 16) + h];
      #pragma unroll
      for (int i = 0; i < 4; ++i)
        #pragma unroll
        for (int j = 0; j < 2; ++j)
          acc[i][j] = __builtin_amdgcn_mfma_f32_16x16x32_fp8_fp8(af[i], bf[j], acc[i][j], 0, 0, 0);
    }

    // --- Phase Q: quantize B(kk+1) (loads had the MFMA phase to land).
    if (kk < 3) {
      f0.x*=16.f; f0.y*=16.f; f0.z*=16.f; f0.w*=16.f;
      f1.x*=16.f; f1.y*=16.f; f1.z*=16.f; f1.w*=16.f;
      f2.x*=16.f; f2.y*=16.f; f2.z*=16.f; f2.w*=16.f;
      f3.x*=16.f; f3.y*=16.f; f3.z*=16.f; f3.w*=16.f;
      ssq = f0.x*f0.x + f0.y*f0.y + f0.z*f0.z + f0.w*f0.w
          + f1.x*f1.x + f1.y*f1.y + f1.z*f1.z + f1.w*f1.w
          + f2.x*f2.x + f2.y*f2.y + f2.z*f2.z + f2.w*f2.w
          + f3.x*f3.x + f3.y*f3.y + f3.z*f3.z + f3.w*f3.w;
      p0 = __builtin_amdgcn_cvt_pk_fp8_f32(f0.x, f0.y, 0, false);
      p0 = __builtin_amdgcn_cvt_pk_fp8_f32(f0.z, f0.w, p0, true);
      p1 = __builtin_amdgcn_cvt_pk_fp8_f32(f1.x, f1.y, 0, false);
      p1 = __builtin_amdgcn_cvt_pk_fp8_f32(f1.z, f1.w, p1, true);
      p2 = __builtin_amdgcn_cvt_pk_fp8_f32(f2.x, f2.y, 0, false);
      p2 = __builtin_amdgcn_cvt_pk_fp8_f32(f2.z, f2.w, p2, true);
      p3 = __builtin_amdgcn_cvt_pk_fp8_f32(f3.x, f3.y, 0, false);
      p3 = __builtin_amdgcn_cvt_pk_fp8_f32(f3.z, f3.w, p3, true);
    }
    __syncthreads();   // all waves' LDS reads of tile kk done; vm queue empty
  }

  // Epilogue: cos = acc/(|16w|*|x|); logit = 64*cos (-22.4 at gt);
  // rowsum += sum_n exp(logit-64).
  float rnw[2];
  #pragma unroll
  for (int j = 0; j < 2; ++j)
    rnw[j] = 1.0f / fmaxf(sqrtf(lds_nw[wn_ * 32 + j * 16 + l15]), 1e-12f);
  #pragma unroll
  for (int i = 0; i < 4; ++i) {
    #pragma unroll
    for (int reg = 0; reg < 4; ++reg) {
      int m_loc = wm * 64 + i * 16 + quad * 4 + reg;
      int gtm = lds_gt[m_loc];
      float rx = 64.0f / lds_nx[m_loc];     // fold SCALE into the division
      float s = 0.f;
      #pragma unroll
      for (int j = 0; j < 2; ++j) {
        int n_g = nt * BN + wn_ * 32 + j * 16 + l15;
        float logit = acc[i][j][reg] * rnw[j] * rx;
        if (n_g == gtm) {
          logit -= 64.f * 0.35f;
          tgt[mt * BM + m_loc] = logit;
        }
        if (n_g < CCLS) s += __expf(logit - 64.f);
      }
      #pragma unroll
      for (int off = 1; off < 16; off <<= 1) s += __shfl_xor(s, off, 64);
      if (l15 == 0) atomicAdd(&lds_rowsum[m_loc], s);
    }
  }
  __syncthreads();
  if (tid < BM)
    partial[(size_t)(mt * BM + tid) * NT + nt] = lds_rowsum[tid];
}

// One wave per row m: sum partial[m][0..NT) (contiguous), emit nll[m].
__global__ __launch_bounds__(64) void nll_rows(const float* __restrict__ partial,
                                               const float* __restrict__ tgt,
                                               float* __restrict__ nll) {
  int m = blockIdx.x;
  int lane = threadIdx.x;
  const float* row = partial + (size_t)m * NT;
  float s = 0.f;
  for (int t = lane; t < NT; t += 64) s += row[t];
  #pragma unroll
  for (int off = 32; off > 0; off >>= 1) s += __shfl_xor(s, off, 64);
  if (lane == 0) nll[m] = (logf(s) + 64.f) - tgt[m];
}

__global__ __launch_bounds__(512) void reduce_mean(const float* __restrict__ nll,
                                                   float* __restrict__ out) {
  __shared__ float red[BATCH];
  int m = threadIdx.x;
  red[m] = nll[m];
  __syncthreads();
  for (int k = 256; k > 0; k >>= 1) {
    if (m < k) red[m] += red[m + k];
    __syncthreads();
  }
  if (m == 0) out[0] = red[0] * (1.0f / BATCH);
}

extern "C" void kernel_launch(void* const* d_in, const int* in_sizes, int n_in,
                              void* d_out, int out_size, void* d_ws, size_t ws_size,
                              hipStream_t stream) {
  const float* x  = (const float*)d_in[0];
  const int*   gt = (const int*)d_in[1];
  const float* wt = (const float*)d_in[2];
  float* out = (float*)d_out;

  char* ws = (char*)d_ws;
  unsigned char* xq = (unsigned char*)ws;            //   262,144 B
  float* nx         = (float*)(ws + 262144);         //     2,048 B
  float* partial    = (float*)(ws + 264192);         // 3,201,024 B (512*1563*4)
  float* tgt        = (float*)(ws + 3465216);        //     2,048 B
  float* nll        = (float*)(ws + 3467264);        //     2,048 B

  xquant<<<BATCH / 4, 256, 0, stream>>>(x, xq, nx);
  cosface_fused<<<2 * NT, 512, 0, stream>>>(xq, wt, gt, nx, partial, tgt);
  nll_rows<<<BATCH, 64, 0, stream>>>(partial, tgt, nll);
  reduce_mean<<<1, BATCH, 0, stream>>>(nll, out);
}